// Round 11
// baseline (339.044 us; speedup 1.0000x reference)
//
#include <hip/hip_runtime.h>

#define NB 4
#define NN 65536
#define NK 16
#define NP (NB * NN)   // 262144 points
#define BN_EPS 1e-6f
#define LOG2E 1.44269504088896f

// ---- workspace layout (floats) ----
#define WS_ENC_M   0    // 27 floats: enc moments basis [c,n,1]
#define WS_SC_M    32   // S_f[8] @32, M_ff upper-tri 36 @40  (44 floats)
#define WS_S_Y2    96   // 8  pool1 conv sum
#define WS_SS_Y2   104  // 8
#define WS_S_Y4    112  // 16 pool2 conv sum
#define WS_SS_Y4   128  // 16 -> raw stats end at 144
// folded-weight tables (written by k_prep): per layer 88 floats
//   fw[0..23]=an, fw[24..47]=dc, fw[48..55]=dk, fw[64..127]=sws (LOG2E-folded)
#define WS_FW1     160
#define WS_FW2     288
#define WS_C4      1024               // NP float4 (4 MB) packed coords
#define WS_NB      (1024 + NP * 4)    // 48 scalar planes (48 MB): [3k+d][p] gathered nbr coords
#define WS_Y2      (1024 + NP * 52)   // 2 float4 planes (8 MB): y2 ch0..7
#define WS_Y4      (1024 + NP * 60)   // 4 float4 planes (16 MB)
// total ws requirement: (1024 + NP*76) floats = ~80 MB

// entry+exit barriers REQUIRED (R5 lesson: LDS overlay races at high occupancy)
template <int NCH>
__device__ inline void blockReduceAtomic(float (&v)[NCH], float* __restrict__ dst) {
    __shared__ float red[4][NCH];
    const int lane = threadIdx.x & 63;
    const int wv = threadIdx.x >> 6;
    __syncthreads();
#pragma unroll
    for (int c = 0; c < NCH; c++) {
        float x = v[c];
#pragma unroll
        for (int off = 32; off > 0; off >>= 1) x += __shfl_xor(x, off, 64);
        if (lane == 0) red[wv][c] = x;
    }
    __syncthreads();
    for (int c = threadIdx.x; c < NCH; c += 256)
        atomicAdd(dst + c, red[0][c] + red[1][c] + red[2][c] + red[3][c]);
    __syncthreads();
}

// bn scale/shift for an lse conv channel from enc moments. w points at 10 weights.
__device__ inline void bn_from_enc(const float* __restrict__ M, const float* __restrict__ w,
                                   float b, float g, float bt, float& sc, float& sh) {
    float u[6];
    u[0] = w[0] + w[6]; u[1] = w[1] + w[7]; u[2] = w[2] + w[8];
    u[3] = w[3] - w[6]; u[4] = w[4] - w[7]; u[5] = w[5] - w[8];
    const float beta = b + w[9];
    float lin = 0.f;
#pragma unroll
    for (int i = 0; i < 6; i++) lin += u[i] * M[i];
    float quad = u[0] * u[0] * M[6] + 2.f * u[0] * u[1] * M[7] + 2.f * u[0] * u[2] * M[8]
               + u[1] * u[1] * M[9] + 2.f * u[1] * u[2] * M[10] + u[2] * u[2] * M[11];
#pragma unroll
    for (int i = 0; i < 3; i++)
#pragma unroll
        for (int j = 0; j < 3; j++) quad += 2.f * u[i] * u[3 + j] * M[12 + i * 3 + j];
    quad += u[3] * u[3] * M[21] + 2.f * u[3] * u[4] * M[22] + 2.f * u[3] * u[5] * M[23]
          + u[4] * u[4] * M[24] + 2.f * u[4] * u[5] * M[25] + u[5] * u[5] * M[26];
    const float cnt = (float)NP * (float)NK;
    const float sum = lin + cnt * beta;
    const float ss = quad + 2.f * beta * lin + cnt * beta * beta;
    const float m = sum / cnt, v = ss / cnt - m * m;
    sc = g * rsqrtf(v + BN_EPS);
    sh = bt - m * sc;
}

// ---------------- Kernel 1a (streaming): pack c4 + shortcut feat moments
__global__ __launch_bounds__(256) void k_pack(
    const float* __restrict__ coords, const float* __restrict__ feats,
    float4* __restrict__ c4, float* __restrict__ ws) {
    const int tid = threadIdx.x;
    const int p = blockIdx.x * 256 + tid;
    const int b = p >> 16;
    const int n = p & (NN - 1);
    c4[p] = make_float4(coords[3 * p], coords[3 * p + 1], coords[3 * p + 2], 0.f);
    float accf[44];
    float f[8];
#pragma unroll
    for (int i = 0; i < 8; i++) f[i] = feats[(b * 8 + i) * NN + n];
#pragma unroll
    for (int i = 0; i < 8; i++) accf[i] = f[i];
    int t2 = 8;
#pragma unroll
    for (int i = 0; i < 8; i++)
#pragma unroll
        for (int j = i; j < 8; j++) accf[t2++] = f[i] * f[j];
    blockReduceAtomic<44>(accf, ws + WS_SC_M);
}

// ---------------- Kernel 1b: THE gather (once), 4-way k-split, 4 points/thread,
// MLP-restructured: phase1 issues all 4 idx loads, phase2 all 16 independent
// gathers (16 outstanding VMEM/wave), phase3 stores + moments.
__global__ __launch_bounds__(256) void k_stats(
    const float4* __restrict__ c4, const int* __restrict__ idx,
    float* __restrict__ ws) {
    const int tid = threadIdx.x;
    const int q = tid & 3;              // quad (k group): k = 4q..4q+3
    const int p0 = blockIdx.x * 256 + (tid >> 2);
    float* __restrict__ nbp = ws + WS_NB;

    // phase 1: all idx loads (coalesced)
    int4 v[4];
#pragma unroll
    for (int it = 0; it < 4; it++)
        v[it] = ((const int4*)idx)[(p0 + it * 64) * 4 + q];

    // phase 2: all 16 gathers, fully independent
    float4 nb[4][4];
#pragma unroll
    for (int it = 0; it < 4; it++) {
        const int boff = ((p0 + it * 64) >> 16) << 16;
        nb[it][0] = c4[boff + v[it].x];
        nb[it][1] = c4[boff + v[it].y];
        nb[it][2] = c4[boff + v[it].z];
        nb[it][3] = c4[boff + v[it].w];
    }

    // phase 3: stores + moments (+ coalesced center loads, latency covered)
    float acc[27];
#pragma unroll
    for (int i = 0; i < 27; i++) acc[i] = 0.f;
#pragma unroll
    for (int it = 0; it < 4; it++) {
        const int p = p0 + it * 64;
        const float4 me = c4[p];
#pragma unroll
        for (int e = 0; e < 4; e++) {
            const int k = 4 * q + e;
            nbp[(3 * k    ) * NP + p] = nb[it][e].x;
            nbp[(3 * k + 1) * NP + p] = nb[it][e].y;
            nbp[(3 * k + 2) * NP + p] = nb[it][e].z;
        }
        float sn0 = 0.f, sn1 = 0.f, sn2 = 0.f;
#pragma unroll
        for (int e = 0; e < 4; e++) {
            const float4 t = nb[it][e];
            sn0 += t.x; sn1 += t.y; sn2 += t.z;
            acc[21] += t.x * t.x; acc[22] += t.x * t.y; acc[23] += t.x * t.z;
            acc[24] += t.y * t.y; acc[25] += t.y * t.z; acc[26] += t.z * t.z;
        }
        // center-point-only terms: each of the 4 quad-threads contributes 4x (16 total)
        acc[0] += 4.f * me.x; acc[1] += 4.f * me.y; acc[2] += 4.f * me.z;
        acc[3] += sn0; acc[4] += sn1; acc[5] += sn2;
        acc[6] += 4.f * me.x * me.x; acc[7] += 4.f * me.x * me.y; acc[8] += 4.f * me.x * me.z;
        acc[9] += 4.f * me.y * me.y; acc[10] += 4.f * me.y * me.z; acc[11] += 4.f * me.z * me.z;
        acc[12] += me.x * sn0; acc[13] += me.x * sn1; acc[14] += me.x * sn2;
        acc[15] += me.y * sn0; acc[16] += me.y * sn1; acc[17] += me.y * sn2;
        acc[18] += me.z * sn0; acc[19] += me.z * sn1; acc[20] += me.z * sn2;
    }
    blockReduceAtomic<27>(acc, ws + WS_ENC_M);
}

// ---------------- Kernel 1c (tiny): fold bn+weights into ws tables.
// fw[0..23]=an, [24..47]=dc, [48..55]=dk, [64..127]=sws*LOG2E  (per layer)
__global__ __launch_bounds__(128) void k_prep(
    const float* __restrict__ lse1_w, const float* __restrict__ lse1_b,
    const float* __restrict__ lse1_g, const float* __restrict__ lse1_bt,
    const float* __restrict__ lse2_w, const float* __restrict__ lse2_b,
    const float* __restrict__ lse2_g, const float* __restrict__ lse2_bt,
    const float* __restrict__ p1_sw, const float* __restrict__ p2_sw,
    float* __restrict__ ws) {
    const int tid = threadIdx.x;
    if (tid < 8) {
        const int c = tid;
        const float* w = lse1_w + c * 10;
        float sc, sh;
        bn_from_enc(ws + WS_ENC_M, w, lse1_b[c], lse1_g[c], lse1_bt[c], sc, sh);
#pragma unroll
        for (int i = 0; i < 3; i++) {
            ws[WS_FW1 + c * 3 + i] = sc * (w[3 + i] - w[6 + i]);       // an
            ws[WS_FW1 + 24 + c * 3 + i] = sc * (w[i] + w[6 + i]);      // dc
        }
        ws[WS_FW1 + 48 + c] = sc * (lse1_b[c] + w[9]) + sh;            // dk
    } else if (tid < 16) {
        const int c = tid - 8;
        const float* w = lse2_w + c * 10;
        float sc, sh;
        bn_from_enc(ws + WS_ENC_M, w, lse2_b[c], lse2_g[c], lse2_bt[c], sc, sh);
#pragma unroll
        for (int i = 0; i < 3; i++) {
            ws[WS_FW2 + c * 3 + i] = sc * (w[3 + i] - w[6 + i]);
            ws[WS_FW2 + 24 + c * 3 + i] = sc * (w[i] + w[6 + i]);
        }
        ws[WS_FW2 + 48 + c] = sc * (lse2_b[c] + w[9]) + sh;
    }
    if (tid < 64) {
        ws[WS_FW1 + 64 + tid] = p1_sw[(tid >> 3) * 16 + (tid & 7)] * LOG2E;
        ws[WS_FW2 + 64 + tid] = p2_sw[(tid >> 3) * 16 + (tid & 7)] * LOG2E;
    }
}

// ---------------- Kernel 2: BOTH LSE layers per thread (round-1 structure) with
// scalar-table sws (round-10 technique): nbuf streamed ONCE, sws in SGPRs.
// Every ingredient individually spill-clean: plane loads (r6), no prefetch (r7),
// scalar sws (r10), per-thread two-layer body (r1).
__global__ __launch_bounds__(256) void k_pools(
    const float4* __restrict__ c4, const float* __restrict__ feats,
    const float* __restrict__ w1, const float* __restrict__ b1,
    const float* __restrict__ fw1,  // = ws + WS_FW1 (restrict: no alias with ws writes)
    const float* __restrict__ fw2,  // = ws + WS_FW2
    const float* __restrict__ p1_w, const float* __restrict__ p1_b,
    const float* __restrict__ p2_w, const float* __restrict__ p2_b,
    float* __restrict__ ws) {
    __shared__ float an1S[24], dc1S[24], dk1S[8], an2S[24], dc2S[24], dk2S[8],
        pws1[128], pws2h[128], pbs1[8], pbs2[16], w1s[64], b1s[8];
    const int tid = threadIdx.x;
    if (tid < 24) {
        an1S[tid] = fw1[tid]; dc1S[tid] = fw1[24 + tid];
        an2S[tid] = fw2[tid]; dc2S[tid] = fw2[24 + tid];
    }
    if (tid < 8) {
        dk1S[tid] = fw1[48 + tid]; dk2S[tid] = fw2[48 + tid];
        b1s[tid] = b1[tid]; pbs1[tid] = p1_b[tid];
    }
    if (tid < 16) pbs2[tid] = p2_b[tid];
    if (tid < 64) w1s[tid] = w1[tid];
    if (tid < 128) {
        pws1[tid] = p1_w[tid];
        pws2h[tid] = p2_w[(tid >> 3) * 16 + (tid & 7)];  // W2[c][o], o<8 (k-half)
    }
    __syncthreads();

    const float* __restrict__ swp1 = fw1 + 64;  // uniform scalar-load tables
    const float* __restrict__ swp2 = fw2 + 64;
    const int p = blockIdx.x * 256 + tid;
    const int b = p >> 16;
    const int n = p & (NN - 1);
    const float* __restrict__ nbp = ws + WS_NB;
    const float4 me = c4[p];
    float d1[8], d2[8];
#pragma unroll
    for (int c = 0; c < 8; c++) {
        d1[c] = dc1S[c * 3] * me.x + dc1S[c * 3 + 1] * me.y + dc1S[c * 3 + 2] * me.z + dk1S[c];
        d2[c] = dc2S[c * 3] * me.x + dc2S[c * 3 + 1] * me.y + dc2S[c * 3 + 2] * me.z + dk2S[c];
    }
    float l1[8] = {}, a1[8] = {}, l2[8] = {}, a2[8] = {};

    auto proc = [&](float nx, float ny, float nz) {
        float h[8];
#pragma unroll
        for (int c = 0; c < 8; c++) {
            float y = an1S[c * 3] * nx + an1S[c * 3 + 1] * ny + an1S[c * 3 + 2] * nz + d1[c];
            h[c] = y > 0.f ? y : 0.f;
        }
#pragma unroll
        for (int o = 0; o < 8; o++) {
            float s = 0.f;
#pragma unroll
            for (int i = 0; i < 8; i++) s += h[i] * swp1[o * 8 + i];
            float e2 = exp2f(s);  // k-const part of score cancels in softmax
            l1[o] += e2; a1[o] += e2 * h[o];
        }
#pragma unroll
        for (int c = 0; c < 8; c++) {
            float y = an2S[c * 3] * nx + an2S[c * 3 + 1] * ny + an2S[c * 3 + 2] * nz + d2[c];
            h[c] = y > 0.f ? y : 0.f;
        }
#pragma unroll
        for (int o = 0; o < 8; o++) {
            float s = 0.f;
#pragma unroll
            for (int i = 0; i < 8; i++) s += h[i] * swp2[o * 8 + i];
            float e2 = exp2f(s);
            l2[o] += e2; a2[o] += e2 * h[o];
        }
    };

    const float* __restrict__ nbq = nbp + p;
#pragma unroll 1
    for (int g = 0; g < 4; g++) {
        float X[4], Y[4], Z[4];
#pragma unroll
        for (int e = 0; e < 4; e++) {
            X[e] = nbq[(size_t)(12 * g + 3 * e    ) * NP];
            Y[e] = nbq[(size_t)(12 * g + 3 * e + 1) * NP];
            Z[e] = nbq[(size_t)(12 * g + 3 * e + 2) * NP];
        }
#pragma unroll
        for (int e = 0; e < 4; e++) proc(X[e], Y[e], Z[e]);
    }

    // real barrier: epilogue weight LDS reads cannot be hoisted above it
    __syncthreads();

    // epilogue A: mlp1 + pool1 conv -> Y2 + stats
    float f[8];
#pragma unroll
    for (int i = 0; i < 8; i++) f[i] = feats[(b * 8 + i) * NN + n];
    float agg[16];
#pragma unroll
    for (int o = 0; o < 8; o++) agg[o] = a1[o] * __builtin_amdgcn_rcpf(l1[o]);
#pragma unroll
    for (int jq = 0; jq < 8; jq++) {
        float y = b1s[jq];
#pragma unroll
        for (int i = 0; i < 8; i++) y += f[i] * w1s[jq * 8 + i];
        agg[8 + jq] = y > 0.f ? y : 0.2f * y;  // LeakyReLU(0.2)
    }
    float st[16], yv[8];
#pragma unroll
    for (int c = 0; c < 8; c++) {
        float y = pbs1[c];
#pragma unroll
        for (int o = 0; o < 16; o++) y += agg[o] * pws1[c * 16 + o];
        yv[c] = y; st[c] = y; st[8 + c] = y * y;
    }
    float4* __restrict__ y2 = (float4*)(ws + WS_Y2);
    y2[0 * NP + p] = make_float4(yv[0], yv[1], yv[2], yv[3]);
    y2[1 * NP + p] = make_float4(yv[4], yv[5], yv[6], yv[7]);

    // epilogue B: pool2 conv k-half -> partial Y4
    float g2[8];
#pragma unroll
    for (int o = 0; o < 8; o++) g2[o] = a2[o] * __builtin_amdgcn_rcpf(l2[o]);
    float4* __restrict__ y4 = (float4*)(ws + WS_Y4);
#pragma unroll
    for (int cq = 0; cq < 4; cq++) {
        float w4[4];
#pragma unroll
        for (int j = 0; j < 4; j++) {
            const int c = cq * 4 + j;
            float y = pbs2[c];
#pragma unroll
            for (int o = 0; o < 8; o++) y += g2[o] * pws2h[c * 8 + o];
            w4[j] = y;
        }
        y4[cq * NP + p] = make_float4(w4[0], w4[1], w4[2], w4[3]);
    }
    blockReduceAtomic<16>(st, ws + WS_S_Y2);
}

// ---------------- Kernel 3 (elementwise): finish y4, bn_p2 raw sums
__global__ __launch_bounds__(256) void k_pool2e(
    const float* __restrict__ p1_g, const float* __restrict__ p1_bt,
    const float* __restrict__ p2_w, float* __restrict__ ws) {
    __shared__ float p1sc[8], p1sh[8], pwsb[128];
    const int tid = threadIdx.x;
    if (tid < 8) {  // bn_p1 from raw sums
        const int c = tid;
        const float cP = 1.f / (float)NP;
        float m = ws[WS_S_Y2 + c] * cP, vv = ws[WS_SS_Y2 + c] * cP - m * m;
        float sc = p1_g[c] * rsqrtf(vv + BN_EPS);
        p1sc[c] = sc; p1sh[c] = p1_bt[c] - m * sc;
    }
    if (tid < 128) pwsb[tid] = p2_w[(tid >> 3) * 16 + 8 + (tid & 7)];  // W2[c][8+o]
    __syncthreads();

    const int p = blockIdx.x * 256 + tid;
    const float4* __restrict__ y2 = (const float4*)(ws + WS_Y2);
    float4* __restrict__ y4 = (float4*)(ws + WS_Y4);
    const float4 v0 = y2[0 * NP + p], v1 = y2[1 * NP + p];
    float x2[8] = {v0.x, v0.y, v0.z, v0.w, v1.x, v1.y, v1.z, v1.w};
#pragma unroll
    for (int c = 0; c < 8; c++) {
        float y = x2[c] * p1sc[c] + p1sh[c];
        x2[c] = y > 0.f ? y : 0.f;
    }
    float st[32];
#pragma unroll
    for (int cq = 0; cq < 4; cq++) {
        float4 v = y4[cq * NP + p];
        float yv[4] = {v.x, v.y, v.z, v.w};
#pragma unroll
        for (int j = 0; j < 4; j++) {
            const int c = cq * 4 + j;
            float y = yv[j];
#pragma unroll
            for (int o = 0; o < 8; o++) y += x2[o] * pwsb[c * 8 + o];
            yv[j] = y; st[c] = y; st[16 + c] = y * y;
        }
        y4[cq * NP + p] = make_float4(yv[0], yv[1], yv[2], yv[3]);
    }
    blockReduceAtomic<32>(st, ws + WS_S_Y4);
}

// ---------------- Kernel 4: x4 = relu(bn(y4)); out = leaky(w2@x4 + b2 + bn(sc_w@feats))
__global__ __launch_bounds__(256) void k_final(
    const float* __restrict__ feats, const float* __restrict__ w2,
    const float* __restrict__ b2, const float* __restrict__ sc_w,
    const float* __restrict__ sc_b, const float* __restrict__ p2_g,
    const float* __restrict__ p2_bt, const float* __restrict__ sc_g,
    const float* __restrict__ sc_bt, const float* __restrict__ ws,
    float* __restrict__ out) {
    __shared__ float w2s[512], b2s[32], scws[256], scbs[32],
        p2sc[16], p2sh[16], scsc[32], scsh[32];
    const int tid = threadIdx.x;
    for (int i = tid; i < 512; i += 256) w2s[i] = w2[i];
    if (tid < 256) scws[tid] = sc_w[tid];
    if (tid < 32) {
        b2s[tid] = b2[tid]; scbs[tid] = sc_b[tid];
        const int c = tid;
        const float* w = sc_w + c * 8;
        const float* S = ws + WS_SC_M;
        float lin = 0.f;
#pragma unroll
        for (int i = 0; i < 8; i++) lin += w[i] * S[i];
        float quad = 0.f;
        int t2 = 0;
#pragma unroll
        for (int i = 0; i < 8; i++)
#pragma unroll
            for (int j = i; j < 8; j++) {
                const float mm = S[8 + t2++];
                quad += (i == j ? 1.f : 2.f) * w[i] * w[j] * mm;
            }
        const float cnt = (float)NP;
        const float bb = sc_b[c];
        const float sum = lin + cnt * bb;
        const float ss = quad + 2.f * bb * lin + cnt * bb * bb;
        const float m = sum / cnt, vv = ss / cnt - m * m;
        const float sc = sc_g[c] * rsqrtf(vv + BN_EPS);
        scsc[c] = sc; scsh[c] = sc_bt[c] - m * sc;
    }
    if (tid < 16) {
        const int c = tid;
        const float cP = 1.f / (float)NP;
        float m = ws[WS_S_Y4 + c] * cP, vv = ws[WS_SS_Y4 + c] * cP - m * m;
        float sc = p2_g[c] * rsqrtf(vv + BN_EPS);
        p2sc[c] = sc; p2sh[c] = p2_bt[c] - m * sc;
    }
    __syncthreads();

    const int p = blockIdx.x * 256 + tid;
    const int b = p >> 16;
    const int n = p & (NN - 1);
    const float4* __restrict__ y4 = (const float4*)(ws + WS_Y4);
    float x4[16];
#pragma unroll
    for (int cq = 0; cq < 4; cq++) {
        const float4 v = y4[cq * NP + p];
        const float yv[4] = {v.x, v.y, v.z, v.w};
#pragma unroll
        for (int j = 0; j < 4; j++) {
            const int c = cq * 4 + j;
            float y = yv[j] * p2sc[c] + p2sh[c];
            x4[c] = y > 0.f ? y : 0.f;
        }
    }
    float f[8];
#pragma unroll
    for (int i = 0; i < 8; i++) f[i] = feats[(b * 8 + i) * NN + n];
#pragma unroll
    for (int c = 0; c < 32; c++) {
        float s = scbs[c];
#pragma unroll
        for (int i = 0; i < 8; i++) s += f[i] * scws[c * 8 + i];
        s = s * scsc[c] + scsh[c];  // bn, no activation
        float m = b2s[c];
#pragma unroll
        for (int o = 0; o < 16; o++) m += x4[o] * w2s[c * 16 + o];
        float vv = m + s;
        out[(b * 32 + c) * NN + n] = vv > 0.f ? vv : 0.01f * vv;  // LeakyReLU(0.01)
    }
}

extern "C" void kernel_launch(void* const* d_in, const int* in_sizes, int n_in,
                              void* d_out, int out_size, void* d_ws, size_t ws_size,
                              hipStream_t stream) {
    (void)in_sizes; (void)n_in; (void)out_size; (void)ws_size;
    const float* coords = (const float*)d_in[0];
    const float* features = (const float*)d_in[1];
    const int* idx = (const int*)d_in[2];
    const float* w1 = (const float*)d_in[3];
    const float* b1 = (const float*)d_in[4];
    const float* lse1_w = (const float*)d_in[5];
    const float* lse1_b = (const float*)d_in[6];
    const float* lse1_g = (const float*)d_in[7];
    const float* lse1_bt = (const float*)d_in[8];
    const float* p1_sw = (const float*)d_in[9];
    const float* p1_w = (const float*)d_in[10];
    const float* p1_b = (const float*)d_in[11];
    const float* p1_g = (const float*)d_in[12];
    const float* p1_bt = (const float*)d_in[13];
    const float* lse2_w = (const float*)d_in[14];
    const float* lse2_b = (const float*)d_in[15];
    const float* lse2_g = (const float*)d_in[16];
    const float* lse2_bt = (const float*)d_in[17];
    const float* p2_sw = (const float*)d_in[18];
    const float* p2_w = (const float*)d_in[19];
    const float* p2_b = (const float*)d_in[20];
    const float* p2_g = (const float*)d_in[21];
    const float* p2_bt = (const float*)d_in[22];
    const float* w2 = (const float*)d_in[23];
    const float* b2 = (const float*)d_in[24];
    const float* sc_w = (const float*)d_in[25];
    const float* sc_b = (const float*)d_in[26];
    const float* sc_g = (const float*)d_in[27];
    const float* sc_bt = (const float*)d_in[28];
    float* ws = (float*)d_ws;
    float* out = (float*)d_out;
    float4* c4 = (float4*)(ws + WS_C4);

    (void)hipMemsetAsync(ws, 0, 144 * sizeof(float), stream);
    k_pack<<<NP / 256, 256, 0, stream>>>(coords, features, c4, ws);
    k_stats<<<NP / 256, 256, 0, stream>>>(c4, idx, ws);
    k_prep<<<1, 128, 0, stream>>>(lse1_w, lse1_b, lse1_g, lse1_bt,
                                  lse2_w, lse2_b, lse2_g, lse2_bt,
                                  p1_sw, p2_sw, ws);
    k_pools<<<NP / 256, 256, 0, stream>>>(c4, features, w1, b1,
                                          ws + WS_FW1, ws + WS_FW2,
                                          p1_w, p1_b, p2_w, p2_b, ws);
    k_pool2e<<<NP / 256, 256, 0, stream>>>(p1_g, p1_bt, p2_w, ws);
    k_final<<<NP / 256, 256, 0, stream>>>(features, w2, b2, sc_w, sc_b, p2_g, p2_bt,
                                          sc_g, sc_bt, ws, out);
}

// Round 12
// 295.236 us; speedup vs baseline: 1.1484x; 1.1484x over previous
//
#include <hip/hip_runtime.h>

#define NB 4
#define NN 65536
#define NK 16
#define NP (NB * NN)   // 262144 points
#define BN_EPS 1e-6f
#define LOG2E 1.44269504088896f

// ---- workspace layout (floats) ----
#define WS_ENC_M   0    // 27 floats: enc moments basis [c,n,1]
#define WS_SC_M    32   // S_f[8] @32, M_ff upper-tri 36 @40  (44 floats)
#define WS_S_Y2    96   // 8  pool1 conv sum
#define WS_SS_Y2   104  // 8
#define WS_S_Y4    112  // 16 pool2 conv sum
#define WS_SS_Y4   128  // 16 -> raw stats end at 144
// folded-weight tables (written by k_prep): per layer 88 floats
//   fw[0..23]=an, fw[24..47]=dc, fw[48..55]=dk, fw[64..127]=sws (LOG2E-folded)
#define WS_FW1     160
#define WS_FW2     288
#define WS_C4      1024               // NP float4 (4 MB) packed coords
#define WS_NB      (1024 + NP * 4)    // 48 scalar planes (48 MB): [3k+d][p] gathered nbr coords
#define WS_Y2      (1024 + NP * 52)   // 2 float4 planes (8 MB): y2 ch0..7
#define WS_Y4      (1024 + NP * 60)   // 4 float4 planes (16 MB)
// total ws requirement: (1024 + NP*76) floats = ~80 MB

// entry+exit barriers REQUIRED (R5 lesson: LDS overlay races at high occupancy)
template <int NCH>
__device__ inline void blockReduceAtomic(float (&v)[NCH], float* __restrict__ dst) {
    __shared__ float red[4][NCH];
    const int lane = threadIdx.x & 63;
    const int wv = threadIdx.x >> 6;
    __syncthreads();
#pragma unroll
    for (int c = 0; c < NCH; c++) {
        float x = v[c];
#pragma unroll
        for (int off = 32; off > 0; off >>= 1) x += __shfl_xor(x, off, 64);
        if (lane == 0) red[wv][c] = x;
    }
    __syncthreads();
    for (int c = threadIdx.x; c < NCH; c += 256)
        atomicAdd(dst + c, red[0][c] + red[1][c] + red[2][c] + red[3][c]);
    __syncthreads();
}

// bn scale/shift for an lse conv channel from enc moments. w points at 10 weights.
__device__ inline void bn_from_enc(const float* __restrict__ M, const float* __restrict__ w,
                                   float b, float g, float bt, float& sc, float& sh) {
    float u[6];
    u[0] = w[0] + w[6]; u[1] = w[1] + w[7]; u[2] = w[2] + w[8];
    u[3] = w[3] - w[6]; u[4] = w[4] - w[7]; u[5] = w[5] - w[8];
    const float beta = b + w[9];
    float lin = 0.f;
#pragma unroll
    for (int i = 0; i < 6; i++) lin += u[i] * M[i];
    float quad = u[0] * u[0] * M[6] + 2.f * u[0] * u[1] * M[7] + 2.f * u[0] * u[2] * M[8]
               + u[1] * u[1] * M[9] + 2.f * u[1] * u[2] * M[10] + u[2] * u[2] * M[11];
#pragma unroll
    for (int i = 0; i < 3; i++)
#pragma unroll
        for (int j = 0; j < 3; j++) quad += 2.f * u[i] * u[3 + j] * M[12 + i * 3 + j];
    quad += u[3] * u[3] * M[21] + 2.f * u[3] * u[4] * M[22] + 2.f * u[3] * u[5] * M[23]
          + u[4] * u[4] * M[24] + 2.f * u[4] * u[5] * M[25] + u[5] * u[5] * M[26];
    const float cnt = (float)NP * (float)NK;
    const float sum = lin + cnt * beta;
    const float ss = quad + 2.f * beta * lin + cnt * beta * beta;
    const float m = sum / cnt, v = ss / cnt - m * m;
    sc = g * rsqrtf(v + BN_EPS);
    sh = bt - m * sc;
}

// ---------------- Kernel 1a (streaming): pack c4 + shortcut feat moments
__global__ __launch_bounds__(256) void k_pack(
    const float* __restrict__ coords, const float* __restrict__ feats,
    float4* __restrict__ c4, float* __restrict__ ws) {
    const int tid = threadIdx.x;
    const int p = blockIdx.x * 256 + tid;
    const int b = p >> 16;
    const int n = p & (NN - 1);
    c4[p] = make_float4(coords[3 * p], coords[3 * p + 1], coords[3 * p + 2], 0.f);
    float accf[44];
    float f[8];
#pragma unroll
    for (int i = 0; i < 8; i++) f[i] = feats[(b * 8 + i) * NN + n];
#pragma unroll
    for (int i = 0; i < 8; i++) accf[i] = f[i];
    int t2 = 8;
#pragma unroll
    for (int i = 0; i < 8; i++)
#pragma unroll
        for (int j = i; j < 8; j++) accf[t2++] = f[i] * f[j];
    blockReduceAtomic<44>(accf, ws + WS_SC_M);
}

// ---------------- Kernel 1b: THE gather (once), 4-way k-split, 4 points/thread,
// MLP-restructured: phase1 issues all 4 idx loads, phase2 all 16 independent
// gathers (16 outstanding VMEM/wave), phase3 stores + moments.
__global__ __launch_bounds__(256) void k_stats(
    const float4* __restrict__ c4, const int* __restrict__ idx,
    float* __restrict__ ws) {
    const int tid = threadIdx.x;
    const int q = tid & 3;              // quad (k group): k = 4q..4q+3
    const int p0 = blockIdx.x * 256 + (tid >> 2);
    float* __restrict__ nbp = ws + WS_NB;

    // phase 1: all idx loads (coalesced)
    int4 v[4];
#pragma unroll
    for (int it = 0; it < 4; it++)
        v[it] = ((const int4*)idx)[(p0 + it * 64) * 4 + q];

    // phase 2: all 16 gathers, fully independent
    float4 nb[4][4];
#pragma unroll
    for (int it = 0; it < 4; it++) {
        const int boff = ((p0 + it * 64) >> 16) << 16;
        nb[it][0] = c4[boff + v[it].x];
        nb[it][1] = c4[boff + v[it].y];
        nb[it][2] = c4[boff + v[it].z];
        nb[it][3] = c4[boff + v[it].w];
    }

    // phase 3: stores + moments (+ coalesced center loads, latency covered)
    float acc[27];
#pragma unroll
    for (int i = 0; i < 27; i++) acc[i] = 0.f;
#pragma unroll
    for (int it = 0; it < 4; it++) {
        const int p = p0 + it * 64;
        const float4 me = c4[p];
#pragma unroll
        for (int e = 0; e < 4; e++) {
            const int k = 4 * q + e;
            nbp[(3 * k    ) * NP + p] = nb[it][e].x;
            nbp[(3 * k + 1) * NP + p] = nb[it][e].y;
            nbp[(3 * k + 2) * NP + p] = nb[it][e].z;
        }
        float sn0 = 0.f, sn1 = 0.f, sn2 = 0.f;
#pragma unroll
        for (int e = 0; e < 4; e++) {
            const float4 t = nb[it][e];
            sn0 += t.x; sn1 += t.y; sn2 += t.z;
            acc[21] += t.x * t.x; acc[22] += t.x * t.y; acc[23] += t.x * t.z;
            acc[24] += t.y * t.y; acc[25] += t.y * t.z; acc[26] += t.z * t.z;
        }
        // center-point-only terms: each of the 4 quad-threads contributes 4x (16 total)
        acc[0] += 4.f * me.x; acc[1] += 4.f * me.y; acc[2] += 4.f * me.z;
        acc[3] += sn0; acc[4] += sn1; acc[5] += sn2;
        acc[6] += 4.f * me.x * me.x; acc[7] += 4.f * me.x * me.y; acc[8] += 4.f * me.x * me.z;
        acc[9] += 4.f * me.y * me.y; acc[10] += 4.f * me.y * me.z; acc[11] += 4.f * me.z * me.z;
        acc[12] += me.x * sn0; acc[13] += me.x * sn1; acc[14] += me.x * sn2;
        acc[15] += me.y * sn0; acc[16] += me.y * sn1; acc[17] += me.y * sn2;
        acc[18] += me.z * sn0; acc[19] += me.z * sn1; acc[20] += me.z * sn2;
    }
    blockReduceAtomic<27>(acc, ws + WS_ENC_M);
}

// ---------------- Kernel 1c (tiny): fold bn+weights into ws tables.
// fw[0..23]=an, [24..47]=dc, [48..55]=dk, [64..127]=sws*LOG2E  (per layer)
__global__ __launch_bounds__(128) void k_prep(
    const float* __restrict__ lse1_w, const float* __restrict__ lse1_b,
    const float* __restrict__ lse1_g, const float* __restrict__ lse1_bt,
    const float* __restrict__ lse2_w, const float* __restrict__ lse2_b,
    const float* __restrict__ lse2_g, const float* __restrict__ lse2_bt,
    const float* __restrict__ p1_sw, const float* __restrict__ p2_sw,
    float* __restrict__ ws) {
    const int tid = threadIdx.x;
    if (tid < 8) {
        const int c = tid;
        const float* w = lse1_w + c * 10;
        float sc, sh;
        bn_from_enc(ws + WS_ENC_M, w, lse1_b[c], lse1_g[c], lse1_bt[c], sc, sh);
#pragma unroll
        for (int i = 0; i < 3; i++) {
            ws[WS_FW1 + c * 3 + i] = sc * (w[3 + i] - w[6 + i]);       // an
            ws[WS_FW1 + 24 + c * 3 + i] = sc * (w[i] + w[6 + i]);      // dc
        }
        ws[WS_FW1 + 48 + c] = sc * (lse1_b[c] + w[9]) + sh;            // dk
    } else if (tid < 16) {
        const int c = tid - 8;
        const float* w = lse2_w + c * 10;
        float sc, sh;
        bn_from_enc(ws + WS_ENC_M, w, lse2_b[c], lse2_g[c], lse2_bt[c], sc, sh);
#pragma unroll
        for (int i = 0; i < 3; i++) {
            ws[WS_FW2 + c * 3 + i] = sc * (w[3 + i] - w[6 + i]);
            ws[WS_FW2 + 24 + c * 3 + i] = sc * (w[i] + w[6 + i]);
        }
        ws[WS_FW2 + 48 + c] = sc * (lse2_b[c] + w[9]) + sh;
    }
    if (tid < 64) {
        ws[WS_FW1 + 64 + tid] = p1_sw[(tid >> 3) * 16 + (tid & 7)] * LOG2E;
        ws[WS_FW2 + 64 + tid] = p2_sw[(tid >> 3) * 16 + (tid & 7)] * LOG2E;
    }
}

// ---------------- Kernel 2: BOTH pools, one dispatch, block-parity split.
// Even blocks: round-10 k_pool1a body; odd blocks: round-10 k_pool1b body.
// Each branch = ONE layer of per-thread state (60 VGPR solo). r9's parity
// fusion failed at VGPR 140 (3 waves/SIMD cap); with scalar sws both bodies
// are ~60 VGPR -> 8 blocks/CU co-residency possible. Adjacent even/odd blocks
// cover the same p-range -> nbuf fetched once per pair via L2.
__global__ __launch_bounds__(256) void k_pools(
    const float4* __restrict__ c4, const float* __restrict__ feats,
    const float* __restrict__ w1, const float* __restrict__ b1,
    const float* __restrict__ fw1,  // = ws + WS_FW1 (restrict: no alias with ws writes)
    const float* __restrict__ fw2,  // = ws + WS_FW2
    const float* __restrict__ p1_w, const float* __restrict__ p1_b,
    const float* __restrict__ p2_w, const float* __restrict__ p2_b,
    float* __restrict__ ws) {
    __shared__ float anS[24], dcS[24], dkS[8], pwsS[128], pbsA[8], w1s[64], b1s[8], pbsB[16];
    const int tid = threadIdx.x;
    const int half = blockIdx.x & 1;
    const int p = (blockIdx.x >> 1) * 256 + tid;
    const float* __restrict__ nbp = ws + WS_NB;
    const float* __restrict__ nbq = nbp + p;

    if (half == 0) {
        // ======== layer-1 branch (byte-wise the r10 k_pool1a body) ========
        if (tid < 24) { anS[tid] = fw1[tid]; dcS[tid] = fw1[24 + tid]; }
        if (tid < 8) { dkS[tid] = fw1[48 + tid]; b1s[tid] = b1[tid]; pbsA[tid] = p1_b[tid]; }
        if (tid < 64) w1s[tid] = w1[tid];
        if (tid < 128) pwsS[tid] = p1_w[tid];
        __syncthreads();

        const float* __restrict__ swp = fw1 + 64;  // uniform scalar-load table
        const int b = p >> 16;
        const int n = p & (NN - 1);
        const float4 me = c4[p];
        float d1[8];
#pragma unroll
        for (int c = 0; c < 8; c++)
            d1[c] = dcS[c * 3] * me.x + dcS[c * 3 + 1] * me.y + dcS[c * 3 + 2] * me.z + dkS[c];
        float l1[8] = {}, a1[8] = {};

        auto proc = [&](float nx, float ny, float nz) {
            float h[8];
#pragma unroll
            for (int c = 0; c < 8; c++) {
                float y = anS[c * 3] * nx + anS[c * 3 + 1] * ny + anS[c * 3 + 2] * nz + d1[c];
                h[c] = y > 0.f ? y : 0.f;
            }
#pragma unroll
            for (int o = 0; o < 8; o++) {
                float s = 0.f;
#pragma unroll
                for (int i = 0; i < 8; i++) s += h[i] * swp[o * 8 + i];
                float e2 = exp2f(s);  // k-const part cancels in softmax
                l1[o] += e2; a1[o] += e2 * h[o];
            }
        };

#pragma unroll 1
        for (int g = 0; g < 4; g++) {
            float X[4], Y[4], Z[4];
#pragma unroll
            for (int e = 0; e < 4; e++) {
                X[e] = nbq[(size_t)(12 * g + 3 * e    ) * NP];
                Y[e] = nbq[(size_t)(12 * g + 3 * e + 1) * NP];
                Z[e] = nbq[(size_t)(12 * g + 3 * e + 2) * NP];
            }
#pragma unroll
            for (int e = 0; e < 4; e++) proc(X[e], Y[e], Z[e]);
        }

        __syncthreads();  // epilogue weights not hoistable above

        float f[8];
#pragma unroll
        for (int i = 0; i < 8; i++) f[i] = feats[(b * 8 + i) * NN + n];
        float agg[16];
#pragma unroll
        for (int o = 0; o < 8; o++) agg[o] = a1[o] * __builtin_amdgcn_rcpf(l1[o]);
#pragma unroll
        for (int jq = 0; jq < 8; jq++) {
            float y = b1s[jq];
#pragma unroll
            for (int i = 0; i < 8; i++) y += f[i] * w1s[jq * 8 + i];
            agg[8 + jq] = y > 0.f ? y : 0.2f * y;  // LeakyReLU(0.2)
        }
        float st[16], yv[8];
#pragma unroll
        for (int c = 0; c < 8; c++) {
            float y = pbsA[c];
#pragma unroll
            for (int o = 0; o < 16; o++) y += agg[o] * pwsS[c * 16 + o];
            yv[c] = y; st[c] = y; st[8 + c] = y * y;
        }
        float4* __restrict__ y2 = (float4*)(ws + WS_Y2);
        y2[0 * NP + p] = make_float4(yv[0], yv[1], yv[2], yv[3]);
        y2[1 * NP + p] = make_float4(yv[4], yv[5], yv[6], yv[7]);
        blockReduceAtomic<16>(st, ws + WS_S_Y2);
    } else {
        // ======== layer-2 branch (byte-wise the r10 k_pool1b body) ========
        if (tid < 24) { anS[tid] = fw2[tid]; dcS[tid] = fw2[24 + tid]; }
        if (tid < 8) dkS[tid] = fw2[48 + tid];
        if (tid < 16) pbsB[tid] = p2_b[tid];
        if (tid < 128) pwsS[tid] = p2_w[(tid >> 3) * 16 + (tid & 7)];  // W2[c][o], o<8
        __syncthreads();

        const float* __restrict__ swp = fw2 + 64;
        const float4 me = c4[p];
        float d2[8];
#pragma unroll
        for (int c = 0; c < 8; c++)
            d2[c] = dcS[c * 3] * me.x + dcS[c * 3 + 1] * me.y + dcS[c * 3 + 2] * me.z + dkS[c];
        float l2[8] = {}, a2[8] = {};

        auto proc = [&](float nx, float ny, float nz) {
            float h[8];
#pragma unroll
            for (int c = 0; c < 8; c++) {
                float y = anS[c * 3] * nx + anS[c * 3 + 1] * ny + anS[c * 3 + 2] * nz + d2[c];
                h[c] = y > 0.f ? y : 0.f;
            }
#pragma unroll
            for (int o = 0; o < 8; o++) {
                float s = 0.f;
#pragma unroll
                for (int i = 0; i < 8; i++) s += h[i] * swp[o * 8 + i];
                float e2 = exp2f(s);
                l2[o] += e2; a2[o] += e2 * h[o];
            }
        };

#pragma unroll 1
        for (int g = 0; g < 4; g++) {
            float X[4], Y[4], Z[4];
#pragma unroll
            for (int e = 0; e < 4; e++) {
                X[e] = nbq[(size_t)(12 * g + 3 * e    ) * NP];
                Y[e] = nbq[(size_t)(12 * g + 3 * e + 1) * NP];
                Z[e] = nbq[(size_t)(12 * g + 3 * e + 2) * NP];
            }
#pragma unroll
            for (int e = 0; e < 4; e++) proc(X[e], Y[e], Z[e]);
        }

        __syncthreads();

        float g2[8];
#pragma unroll
        for (int o = 0; o < 8; o++) g2[o] = a2[o] * __builtin_amdgcn_rcpf(l2[o]);
        float4* __restrict__ y4 = (float4*)(ws + WS_Y4);
#pragma unroll
        for (int cq = 0; cq < 4; cq++) {
            float w4[4];
#pragma unroll
            for (int j = 0; j < 4; j++) {
                const int c = cq * 4 + j;
                float y = pbsB[c];
#pragma unroll
                for (int o = 0; o < 8; o++) y += g2[o] * pwsS[c * 8 + o];
                w4[j] = y;
            }
            y4[cq * NP + p] = make_float4(w4[0], w4[1], w4[2], w4[3]);
        }
    }
}

// ---------------- Kernel 3 (elementwise): finish y4, bn_p2 raw sums
__global__ __launch_bounds__(256) void k_pool2e(
    const float* __restrict__ p1_g, const float* __restrict__ p1_bt,
    const float* __restrict__ p2_w, float* __restrict__ ws) {
    __shared__ float p1sc[8], p1sh[8], pwsb[128];
    const int tid = threadIdx.x;
    if (tid < 8) {  // bn_p1 from raw sums
        const int c = tid;
        const float cP = 1.f / (float)NP;
        float m = ws[WS_S_Y2 + c] * cP, vv = ws[WS_SS_Y2 + c] * cP - m * m;
        float sc = p1_g[c] * rsqrtf(vv + BN_EPS);
        p1sc[c] = sc; p1sh[c] = p1_bt[c] - m * sc;
    }
    if (tid < 128) pwsb[tid] = p2_w[(tid >> 3) * 16 + 8 + (tid & 7)];  // W2[c][8+o]
    __syncthreads();

    const int p = blockIdx.x * 256 + tid;
    const float4* __restrict__ y2 = (const float4*)(ws + WS_Y2);
    float4* __restrict__ y4 = (float4*)(ws + WS_Y4);
    const float4 v0 = y2[0 * NP + p], v1 = y2[1 * NP + p];
    float x2[8] = {v0.x, v0.y, v0.z, v0.w, v1.x, v1.y, v1.z, v1.w};
#pragma unroll
    for (int c = 0; c < 8; c++) {
        float y = x2[c] * p1sc[c] + p1sh[c];
        x2[c] = y > 0.f ? y : 0.f;
    }
    float st[32];
#pragma unroll
    for (int cq = 0; cq < 4; cq++) {
        float4 v = y4[cq * NP + p];
        float yv[4] = {v.x, v.y, v.z, v.w};
#pragma unroll
        for (int j = 0; j < 4; j++) {
            const int c = cq * 4 + j;
            float y = yv[j];
#pragma unroll
            for (int o = 0; o < 8; o++) y += x2[o] * pwsb[c * 8 + o];
            yv[j] = y; st[c] = y; st[16 + c] = y * y;
        }
        y4[cq * NP + p] = make_float4(yv[0], yv[1], yv[2], yv[3]);
    }
    blockReduceAtomic<32>(st, ws + WS_S_Y4);
}

// ---------------- Kernel 4: x4 = relu(bn(y4)); out = leaky(w2@x4 + b2 + bn(sc_w@feats))
__global__ __launch_bounds__(256) void k_final(
    const float* __restrict__ feats, const float* __restrict__ w2,
    const float* __restrict__ b2, const float* __restrict__ sc_w,
    const float* __restrict__ sc_b, const float* __restrict__ p2_g,
    const float* __restrict__ p2_bt, const float* __restrict__ sc_g,
    const float* __restrict__ sc_bt, const float* __restrict__ ws,
    float* __restrict__ out) {
    __shared__ float w2s[512], b2s[32], scws[256], scbs[32],
        p2sc[16], p2sh[16], scsc[32], scsh[32];
    const int tid = threadIdx.x;
    for (int i = tid; i < 512; i += 256) w2s[i] = w2[i];
    if (tid < 256) scws[tid] = sc_w[tid];
    if (tid < 32) {
        b2s[tid] = b2[tid]; scbs[tid] = sc_b[tid];
        const int c = tid;
        const float* w = sc_w + c * 8;
        const float* S = ws + WS_SC_M;
        float lin = 0.f;
#pragma unroll
        for (int i = 0; i < 8; i++) lin += w[i] * S[i];
        float quad = 0.f;
        int t2 = 0;
#pragma unroll
        for (int i = 0; i < 8; i++)
#pragma unroll
            for (int j = i; j < 8; j++) {
                const float mm = S[8 + t2++];
                quad += (i == j ? 1.f : 2.f) * w[i] * w[j] * mm;
            }
        const float cnt = (float)NP;
        const float bb = sc_b[c];
        const float sum = lin + cnt * bb;
        const float ss = quad + 2.f * bb * lin + cnt * bb * bb;
        const float m = sum / cnt, vv = ss / cnt - m * m;
        const float sc = sc_g[c] * rsqrtf(vv + BN_EPS);
        scsc[c] = sc; scsh[c] = sc_bt[c] - m * sc;
    }
    if (tid < 16) {
        const int c = tid;
        const float cP = 1.f / (float)NP;
        float m = ws[WS_S_Y4 + c] * cP, vv = ws[WS_SS_Y4 + c] * cP - m * m;
        float sc = p2_g[c] * rsqrtf(vv + BN_EPS);
        p2sc[c] = sc; p2sh[c] = p2_bt[c] - m * sc;
    }
    __syncthreads();

    const int p = blockIdx.x * 256 + tid;
    const int b = p >> 16;
    const int n = p & (NN - 1);
    const float4* __restrict__ y4 = (const float4*)(ws + WS_Y4);
    float x4[16];
#pragma unroll
    for (int cq = 0; cq < 4; cq++) {
        const float4 v = y4[cq * NP + p];
        const float yv[4] = {v.x, v.y, v.z, v.w};
#pragma unroll
        for (int j = 0; j < 4; j++) {
            const int c = cq * 4 + j;
            float y = yv[j] * p2sc[c] + p2sh[c];
            x4[c] = y > 0.f ? y : 0.f;
        }
    }
    float f[8];
#pragma unroll
    for (int i = 0; i < 8; i++) f[i] = feats[(b * 8 + i) * NN + n];
#pragma unroll
    for (int c = 0; c < 32; c++) {
        float s = scbs[c];
#pragma unroll
        for (int i = 0; i < 8; i++) s += f[i] * scws[c * 8 + i];
        s = s * scsc[c] + scsh[c];  // bn, no activation
        float m = b2s[c];
#pragma unroll
        for (int o = 0; o < 16; o++) m += x4[o] * w2s[c * 16 + o];
        float vv = m + s;
        out[(b * 32 + c) * NN + n] = vv > 0.f ? vv : 0.01f * vv;  // LeakyReLU(0.01)
    }
}

extern "C" void kernel_launch(void* const* d_in, const int* in_sizes, int n_in,
                              void* d_out, int out_size, void* d_ws, size_t ws_size,
                              hipStream_t stream) {
    (void)in_sizes; (void)n_in; (void)out_size; (void)ws_size;
    const float* coords = (const float*)d_in[0];
    const float* features = (const float*)d_in[1];
    const int* idx = (const int*)d_in[2];
    const float* w1 = (const float*)d_in[3];
    const float* b1 = (const float*)d_in[4];
    const float* lse1_w = (const float*)d_in[5];
    const float* lse1_b = (const float*)d_in[6];
    const float* lse1_g = (const float*)d_in[7];
    const float* lse1_bt = (const float*)d_in[8];
    const float* p1_sw = (const float*)d_in[9];
    const float* p1_w = (const float*)d_in[10];
    const float* p1_b = (const float*)d_in[11];
    const float* p1_g = (const float*)d_in[12];
    const float* p1_bt = (const float*)d_in[13];
    const float* lse2_w = (const float*)d_in[14];
    const float* lse2_b = (const float*)d_in[15];
    const float* lse2_g = (const float*)d_in[16];
    const float* lse2_bt = (const float*)d_in[17];
    const float* p2_sw = (const float*)d_in[18];
    const float* p2_w = (const float*)d_in[19];
    const float* p2_b = (const float*)d_in[20];
    const float* p2_g = (const float*)d_in[21];
    const float* p2_bt = (const float*)d_in[22];
    const float* w2 = (const float*)d_in[23];
    const float* b2 = (const float*)d_in[24];
    const float* sc_w = (const float*)d_in[25];
    const float* sc_b = (const float*)d_in[26];
    const float* sc_g = (const float*)d_in[27];
    const float* sc_bt = (const float*)d_in[28];
    float* ws = (float*)d_ws;
    float* out = (float*)d_out;
    float4* c4 = (float4*)(ws + WS_C4);

    (void)hipMemsetAsync(ws, 0, 144 * sizeof(float), stream);
    k_pack<<<NP / 256, 256, 0, stream>>>(coords, features, c4, ws);
    k_stats<<<NP / 256, 256, 0, stream>>>(c4, idx, ws);
    k_prep<<<1, 128, 0, stream>>>(lse1_w, lse1_b, lse1_g, lse1_bt,
                                  lse2_w, lse2_b, lse2_g, lse2_bt,
                                  p1_sw, p2_sw, ws);
    k_pools<<<2 * (NP / 256), 256, 0, stream>>>(c4, features, w1, b1,
                                                ws + WS_FW1, ws + WS_FW2,
                                                p1_w, p1_b, p2_w, p2_b, ws);
    k_pool2e<<<NP / 256, 256, 0, stream>>>(p1_g, p1_bt, p2_w, ws);
    k_final<<<NP / 256, 256, 0, stream>>>(features, w2, b2, sc_w, sc_b, p2_g, p2_bt,
                                          sc_g, sc_bt, ws, out);
}

// Round 13
// 292.660 us; speedup vs baseline: 1.1585x; 1.0088x over previous
//
#include <hip/hip_runtime.h>

#define NB 4
#define NN 65536
#define NK 16
#define NP (NB * NN)   // 262144 points
#define BN_EPS 1e-6f
#define LOG2E 1.44269504088896f

// ---- workspace layout (floats) ----
#define WS_ENC_M   0    // 27 floats: enc moments basis [c,n,1]
#define WS_SC_M    32   // S_f[8] @32, M_ff upper-tri 36 @40  (44 floats)
#define WS_S_Y2    96   // 8  pool1 conv sum
#define WS_SS_Y2   104  // 8
#define WS_S_Y4    112  // 16 pool2 conv sum
#define WS_SS_Y4   128  // 16 -> raw stats end at 144
// folded-weight tables (written by k_prep): per layer 88 floats
//   fw[0..23]=an, fw[24..47]=dc, fw[48..55]=dk, fw[64..127]=sws (LOG2E-folded)
#define WS_FW1     160
#define WS_FW2     288
#define WS_C4      1024               // NP float4 (4 MB) packed coords
#define WS_NB      (1024 + NP * 4)    // 48 scalar planes (48 MB): [3k+d][p] gathered nbr coords
#define WS_Y2      (1024 + NP * 52)   // 2 float4 planes (8 MB): y2 ch0..7
#define WS_Y4      (1024 + NP * 60)   // 4 float4 planes (16 MB)
// total ws requirement: (1024 + NP*76) floats = ~80 MB

// entry+exit barriers REQUIRED (R5 lesson: LDS overlay races at high occupancy)
template <int NCH>
__device__ inline void blockReduceAtomic(float (&v)[NCH], float* __restrict__ dst) {
    __shared__ float red[4][NCH];
    const int lane = threadIdx.x & 63;
    const int wv = threadIdx.x >> 6;
    __syncthreads();
#pragma unroll
    for (int c = 0; c < NCH; c++) {
        float x = v[c];
#pragma unroll
        for (int off = 32; off > 0; off >>= 1) x += __shfl_xor(x, off, 64);
        if (lane == 0) red[wv][c] = x;
    }
    __syncthreads();
    for (int c = threadIdx.x; c < NCH; c += 256)
        atomicAdd(dst + c, red[0][c] + red[1][c] + red[2][c] + red[3][c]);
    __syncthreads();
}

// bn scale/shift for an lse conv channel from enc moments. w points at 10 weights.
__device__ inline void bn_from_enc(const float* __restrict__ M, const float* __restrict__ w,
                                   float b, float g, float bt, float& sc, float& sh) {
    float u[6];
    u[0] = w[0] + w[6]; u[1] = w[1] + w[7]; u[2] = w[2] + w[8];
    u[3] = w[3] - w[6]; u[4] = w[4] - w[7]; u[5] = w[5] - w[8];
    const float beta = b + w[9];
    float lin = 0.f;
#pragma unroll
    for (int i = 0; i < 6; i++) lin += u[i] * M[i];
    float quad = u[0] * u[0] * M[6] + 2.f * u[0] * u[1] * M[7] + 2.f * u[0] * u[2] * M[8]
               + u[1] * u[1] * M[9] + 2.f * u[1] * u[2] * M[10] + u[2] * u[2] * M[11];
#pragma unroll
    for (int i = 0; i < 3; i++)
#pragma unroll
        for (int j = 0; j < 3; j++) quad += 2.f * u[i] * u[3 + j] * M[12 + i * 3 + j];
    quad += u[3] * u[3] * M[21] + 2.f * u[3] * u[4] * M[22] + 2.f * u[3] * u[5] * M[23]
          + u[4] * u[4] * M[24] + 2.f * u[4] * u[5] * M[25] + u[5] * u[5] * M[26];
    const float cnt = (float)NP * (float)NK;
    const float sum = lin + cnt * beta;
    const float ss = quad + 2.f * beta * lin + cnt * beta * beta;
    const float m = sum / cnt, v = ss / cnt - m * m;
    sc = g * rsqrtf(v + BN_EPS);
    sh = bt - m * sc;
}

// ---------------- Kernel 1a (streaming): pack c4 + shortcut feat moments
__global__ __launch_bounds__(256) void k_pack(
    const float* __restrict__ coords, const float* __restrict__ feats,
    float4* __restrict__ c4, float* __restrict__ ws) {
    const int tid = threadIdx.x;
    const int p = blockIdx.x * 256 + tid;
    const int b = p >> 16;
    const int n = p & (NN - 1);
    c4[p] = make_float4(coords[3 * p], coords[3 * p + 1], coords[3 * p + 2], 0.f);
    float accf[44];
    float f[8];
#pragma unroll
    for (int i = 0; i < 8; i++) f[i] = feats[(b * 8 + i) * NN + n];
#pragma unroll
    for (int i = 0; i < 8; i++) accf[i] = f[i];
    int t2 = 8;
#pragma unroll
    for (int i = 0; i < 8; i++)
#pragma unroll
        for (int j = i; j < 8; j++) accf[t2++] = f[i] * f[j];
    blockReduceAtomic<44>(accf, ws + WS_SC_M);
}

// ---------------- Kernel 1b: THE gather (once), 4-way k-split, 4 points/thread,
// MLP-restructured: phase1 issues all 4 idx loads, phase2 all 16 independent
// gathers (16 outstanding VMEM/wave), phase3 stores + moments.
__global__ __launch_bounds__(256) void k_stats(
    const float4* __restrict__ c4, const int* __restrict__ idx,
    float* __restrict__ ws) {
    const int tid = threadIdx.x;
    const int q = tid & 3;              // quad (k group): k = 4q..4q+3
    const int p0 = blockIdx.x * 256 + (tid >> 2);
    float* __restrict__ nbp = ws + WS_NB;

    // phase 1: all idx loads (coalesced)
    int4 v[4];
#pragma unroll
    for (int it = 0; it < 4; it++)
        v[it] = ((const int4*)idx)[(p0 + it * 64) * 4 + q];

    // phase 2: all 16 gathers, fully independent
    float4 nb[4][4];
#pragma unroll
    for (int it = 0; it < 4; it++) {
        const int boff = ((p0 + it * 64) >> 16) << 16;
        nb[it][0] = c4[boff + v[it].x];
        nb[it][1] = c4[boff + v[it].y];
        nb[it][2] = c4[boff + v[it].z];
        nb[it][3] = c4[boff + v[it].w];
    }

    // phase 3: stores + moments (+ coalesced center loads, latency covered)
    float acc[27];
#pragma unroll
    for (int i = 0; i < 27; i++) acc[i] = 0.f;
#pragma unroll
    for (int it = 0; it < 4; it++) {
        const int p = p0 + it * 64;
        const float4 me = c4[p];
#pragma unroll
        for (int e = 0; e < 4; e++) {
            const int k = 4 * q + e;
            nbp[(3 * k    ) * NP + p] = nb[it][e].x;
            nbp[(3 * k + 1) * NP + p] = nb[it][e].y;
            nbp[(3 * k + 2) * NP + p] = nb[it][e].z;
        }
        float sn0 = 0.f, sn1 = 0.f, sn2 = 0.f;
#pragma unroll
        for (int e = 0; e < 4; e++) {
            const float4 t = nb[it][e];
            sn0 += t.x; sn1 += t.y; sn2 += t.z;
            acc[21] += t.x * t.x; acc[22] += t.x * t.y; acc[23] += t.x * t.z;
            acc[24] += t.y * t.y; acc[25] += t.y * t.z; acc[26] += t.z * t.z;
        }
        // center-point-only terms: each of the 4 quad-threads contributes 4x (16 total)
        acc[0] += 4.f * me.x; acc[1] += 4.f * me.y; acc[2] += 4.f * me.z;
        acc[3] += sn0; acc[4] += sn1; acc[5] += sn2;
        acc[6] += 4.f * me.x * me.x; acc[7] += 4.f * me.x * me.y; acc[8] += 4.f * me.x * me.z;
        acc[9] += 4.f * me.y * me.y; acc[10] += 4.f * me.y * me.z; acc[11] += 4.f * me.z * me.z;
        acc[12] += me.x * sn0; acc[13] += me.x * sn1; acc[14] += me.x * sn2;
        acc[15] += me.y * sn0; acc[16] += me.y * sn1; acc[17] += me.y * sn2;
        acc[18] += me.z * sn0; acc[19] += me.z * sn1; acc[20] += me.z * sn2;
    }
    blockReduceAtomic<27>(acc, ws + WS_ENC_M);
}

// ---------------- Kernel 1c (tiny): fold bn+weights into ws tables.
// fw[0..23]=an, [24..47]=dc, [48..55]=dk, [64..127]=sws*LOG2E  (per layer)
__global__ __launch_bounds__(128) void k_prep(
    const float* __restrict__ lse1_w, const float* __restrict__ lse1_b,
    const float* __restrict__ lse1_g, const float* __restrict__ lse1_bt,
    const float* __restrict__ lse2_w, const float* __restrict__ lse2_b,
    const float* __restrict__ lse2_g, const float* __restrict__ lse2_bt,
    const float* __restrict__ p1_sw, const float* __restrict__ p2_sw,
    float* __restrict__ ws) {
    const int tid = threadIdx.x;
    if (tid < 8) {
        const int c = tid;
        const float* w = lse1_w + c * 10;
        float sc, sh;
        bn_from_enc(ws + WS_ENC_M, w, lse1_b[c], lse1_g[c], lse1_bt[c], sc, sh);
#pragma unroll
        for (int i = 0; i < 3; i++) {
            ws[WS_FW1 + c * 3 + i] = sc * (w[3 + i] - w[6 + i]);       // an
            ws[WS_FW1 + 24 + c * 3 + i] = sc * (w[i] + w[6 + i]);      // dc
        }
        ws[WS_FW1 + 48 + c] = sc * (lse1_b[c] + w[9]) + sh;            // dk
    } else if (tid < 16) {
        const int c = tid - 8;
        const float* w = lse2_w + c * 10;
        float sc, sh;
        bn_from_enc(ws + WS_ENC_M, w, lse2_b[c], lse2_g[c], lse2_bt[c], sc, sh);
#pragma unroll
        for (int i = 0; i < 3; i++) {
            ws[WS_FW2 + c * 3 + i] = sc * (w[3 + i] - w[6 + i]);
            ws[WS_FW2 + 24 + c * 3 + i] = sc * (w[i] + w[6 + i]);
        }
        ws[WS_FW2 + 48 + c] = sc * (lse2_b[c] + w[9]) + sh;
    }
    if (tid < 64) {
        ws[WS_FW1 + 64 + tid] = p1_sw[(tid >> 3) * 16 + (tid & 7)] * LOG2E;
        ws[WS_FW2 + 64 + tid] = p2_sw[(tid >> 3) * 16 + (tid & 7)] * LOG2E;
    }
}

// ---------------- Kernel 2: BOTH pools, one dispatch, block-parity split.
// Round-12 proven structure; ONLY change: exp2f -> __builtin_amdgcn_exp2f
// (bare v_exp_f32, no libm guard code) — tested in isolation for the first time.
__global__ __launch_bounds__(256) void k_pools(
    const float4* __restrict__ c4, const float* __restrict__ feats,
    const float* __restrict__ w1, const float* __restrict__ b1,
    const float* __restrict__ fw1,  // = ws + WS_FW1 (restrict: no alias with ws writes)
    const float* __restrict__ fw2,  // = ws + WS_FW2
    const float* __restrict__ p1_w, const float* __restrict__ p1_b,
    const float* __restrict__ p2_w, const float* __restrict__ p2_b,
    float* __restrict__ ws) {
    __shared__ float anS[24], dcS[24], dkS[8], pwsS[128], pbsA[8], w1s[64], b1s[8], pbsB[16];
    const int tid = threadIdx.x;
    const int half = blockIdx.x & 1;
    const int p = (blockIdx.x >> 1) * 256 + tid;
    const float* __restrict__ nbp = ws + WS_NB;
    const float* __restrict__ nbq = nbp + p;

    if (half == 0) {
        // ======== layer-1 branch ========
        if (tid < 24) { anS[tid] = fw1[tid]; dcS[tid] = fw1[24 + tid]; }
        if (tid < 8) { dkS[tid] = fw1[48 + tid]; b1s[tid] = b1[tid]; pbsA[tid] = p1_b[tid]; }
        if (tid < 64) w1s[tid] = w1[tid];
        if (tid < 128) pwsS[tid] = p1_w[tid];
        __syncthreads();

        const float* __restrict__ swp = fw1 + 64;  // uniform scalar-load table
        const int b = p >> 16;
        const int n = p & (NN - 1);
        const float4 me = c4[p];
        float d1[8];
#pragma unroll
        for (int c = 0; c < 8; c++)
            d1[c] = dcS[c * 3] * me.x + dcS[c * 3 + 1] * me.y + dcS[c * 3 + 2] * me.z + dkS[c];
        float l1[8] = {}, a1[8] = {};

        auto proc = [&](float nx, float ny, float nz) {
            float h[8];
#pragma unroll
            for (int c = 0; c < 8; c++) {
                float y = anS[c * 3] * nx + anS[c * 3 + 1] * ny + anS[c * 3 + 2] * nz + d1[c];
                h[c] = y > 0.f ? y : 0.f;
            }
#pragma unroll
            for (int o = 0; o < 8; o++) {
                float s = 0.f;
#pragma unroll
                for (int i = 0; i < 8; i++) s += h[i] * swp[o * 8 + i];
                float e2 = __builtin_amdgcn_exp2f(s);  // k-const part cancels in softmax
                l1[o] += e2; a1[o] += e2 * h[o];
            }
        };

#pragma unroll 1
        for (int g = 0; g < 4; g++) {
            float X[4], Y[4], Z[4];
#pragma unroll
            for (int e = 0; e < 4; e++) {
                X[e] = nbq[(size_t)(12 * g + 3 * e    ) * NP];
                Y[e] = nbq[(size_t)(12 * g + 3 * e + 1) * NP];
                Z[e] = nbq[(size_t)(12 * g + 3 * e + 2) * NP];
            }
#pragma unroll
            for (int e = 0; e < 4; e++) proc(X[e], Y[e], Z[e]);
        }

        __syncthreads();  // epilogue weights not hoistable above

        float f[8];
#pragma unroll
        for (int i = 0; i < 8; i++) f[i] = feats[(b * 8 + i) * NN + n];
        float agg[16];
#pragma unroll
        for (int o = 0; o < 8; o++) agg[o] = a1[o] * __builtin_amdgcn_rcpf(l1[o]);
#pragma unroll
        for (int jq = 0; jq < 8; jq++) {
            float y = b1s[jq];
#pragma unroll
            for (int i = 0; i < 8; i++) y += f[i] * w1s[jq * 8 + i];
            agg[8 + jq] = y > 0.f ? y : 0.2f * y;  // LeakyReLU(0.2)
        }
        float st[16], yv[8];
#pragma unroll
        for (int c = 0; c < 8; c++) {
            float y = pbsA[c];
#pragma unroll
            for (int o = 0; o < 16; o++) y += agg[o] * pwsS[c * 16 + o];
            yv[c] = y; st[c] = y; st[8 + c] = y * y;
        }
        float4* __restrict__ y2 = (float4*)(ws + WS_Y2);
        y2[0 * NP + p] = make_float4(yv[0], yv[1], yv[2], yv[3]);
        y2[1 * NP + p] = make_float4(yv[4], yv[5], yv[6], yv[7]);
        blockReduceAtomic<16>(st, ws + WS_S_Y2);
    } else {
        // ======== layer-2 branch ========
        if (tid < 24) { anS[tid] = fw2[tid]; dcS[tid] = fw2[24 + tid]; }
        if (tid < 8) dkS[tid] = fw2[48 + tid];
        if (tid < 16) pbsB[tid] = p2_b[tid];
        if (tid < 128) pwsS[tid] = p2_w[(tid >> 3) * 16 + (tid & 7)];  // W2[c][o], o<8
        __syncthreads();

        const float* __restrict__ swp = fw2 + 64;
        const float4 me = c4[p];
        float d2[8];
#pragma unroll
        for (int c = 0; c < 8; c++)
            d2[c] = dcS[c * 3] * me.x + dcS[c * 3 + 1] * me.y + dcS[c * 3 + 2] * me.z + dkS[c];
        float l2[8] = {}, a2[8] = {};

        auto proc = [&](float nx, float ny, float nz) {
            float h[8];
#pragma unroll
            for (int c = 0; c < 8; c++) {
                float y = anS[c * 3] * nx + anS[c * 3 + 1] * ny + anS[c * 3 + 2] * nz + d2[c];
                h[c] = y > 0.f ? y : 0.f;
            }
#pragma unroll
            for (int o = 0; o < 8; o++) {
                float s = 0.f;
#pragma unroll
                for (int i = 0; i < 8; i++) s += h[i] * swp[o * 8 + i];
                float e2 = __builtin_amdgcn_exp2f(s);
                l2[o] += e2; a2[o] += e2 * h[o];
            }
        };

#pragma unroll 1
        for (int g = 0; g < 4; g++) {
            float X[4], Y[4], Z[4];
#pragma unroll
            for (int e = 0; e < 4; e++) {
                X[e] = nbq[(size_t)(12 * g + 3 * e    ) * NP];
                Y[e] = nbq[(size_t)(12 * g + 3 * e + 1) * NP];
                Z[e] = nbq[(size_t)(12 * g + 3 * e + 2) * NP];
            }
#pragma unroll
            for (int e = 0; e < 4; e++) proc(X[e], Y[e], Z[e]);
        }

        __syncthreads();

        float g2[8];
#pragma unroll
        for (int o = 0; o < 8; o++) g2[o] = a2[o] * __builtin_amdgcn_rcpf(l2[o]);
        float4* __restrict__ y4 = (float4*)(ws + WS_Y4);
#pragma unroll
        for (int cq = 0; cq < 4; cq++) {
            float w4[4];
#pragma unroll
            for (int j = 0; j < 4; j++) {
                const int c = cq * 4 + j;
                float y = pbsB[c];
#pragma unroll
                for (int o = 0; o < 8; o++) y += g2[o] * pwsS[c * 8 + o];
                w4[j] = y;
            }
            y4[cq * NP + p] = make_float4(w4[0], w4[1], w4[2], w4[3]);
        }
    }
}

// ---------------- Kernel 3 (elementwise): finish y4, bn_p2 raw sums
__global__ __launch_bounds__(256) void k_pool2e(
    const float* __restrict__ p1_g, const float* __restrict__ p1_bt,
    const float* __restrict__ p2_w, float* __restrict__ ws) {
    __shared__ float p1sc[8], p1sh[8], pwsb[128];
    const int tid = threadIdx.x;
    if (tid < 8) {  // bn_p1 from raw sums
        const int c = tid;
        const float cP = 1.f / (float)NP;
        float m = ws[WS_S_Y2 + c] * cP, vv = ws[WS_SS_Y2 + c] * cP - m * m;
        float sc = p1_g[c] * rsqrtf(vv + BN_EPS);
        p1sc[c] = sc; p1sh[c] = p1_bt[c] - m * sc;
    }
    if (tid < 128) pwsb[tid] = p2_w[(tid >> 3) * 16 + 8 + (tid & 7)];  // W2[c][8+o]
    __syncthreads();

    const int p = blockIdx.x * 256 + tid;
    const float4* __restrict__ y2 = (const float4*)(ws + WS_Y2);
    float4* __restrict__ y4 = (float4*)(ws + WS_Y4);
    const float4 v0 = y2[0 * NP + p], v1 = y2[1 * NP + p];
    float x2[8] = {v0.x, v0.y, v0.z, v0.w, v1.x, v1.y, v1.z, v1.w};
#pragma unroll
    for (int c = 0; c < 8; c++) {
        float y = x2[c] * p1sc[c] + p1sh[c];
        x2[c] = y > 0.f ? y : 0.f;
    }
    float st[32];
#pragma unroll
    for (int cq = 0; cq < 4; cq++) {
        float4 v = y4[cq * NP + p];
        float yv[4] = {v.x, v.y, v.z, v.w};
#pragma unroll
        for (int j = 0; j < 4; j++) {
            const int c = cq * 4 + j;
            float y = yv[j];
#pragma unroll
            for (int o = 0; o < 8; o++) y += x2[o] * pwsb[c * 8 + o];
            yv[j] = y; st[c] = y; st[16 + c] = y * y;
        }
        y4[cq * NP + p] = make_float4(yv[0], yv[1], yv[2], yv[3]);
    }
    blockReduceAtomic<32>(st, ws + WS_S_Y4);
}

// ---------------- Kernel 4: x4 = relu(bn(y4)); out = leaky(w2@x4 + b2 + bn(sc_w@feats))
__global__ __launch_bounds__(256) void k_final(
    const float* __restrict__ feats, const float* __restrict__ w2,
    const float* __restrict__ b2, const float* __restrict__ sc_w,
    const float* __restrict__ sc_b, const float* __restrict__ p2_g,
    const float* __restrict__ p2_bt, const float* __restrict__ sc_g,
    const float* __restrict__ sc_bt, const float* __restrict__ ws,
    float* __restrict__ out) {
    __shared__ float w2s[512], b2s[32], scws[256], scbs[32],
        p2sc[16], p2sh[16], scsc[32], scsh[32];
    const int tid = threadIdx.x;
    for (int i = tid; i < 512; i += 256) w2s[i] = w2[i];
    if (tid < 256) scws[tid] = sc_w[tid];
    if (tid < 32) {
        b2s[tid] = b2[tid]; scbs[tid] = sc_b[tid];
        const int c = tid;
        const float* w = sc_w + c * 8;
        const float* S = ws + WS_SC_M;
        float lin = 0.f;
#pragma unroll
        for (int i = 0; i < 8; i++) lin += w[i] * S[i];
        float quad = 0.f;
        int t2 = 0;
#pragma unroll
        for (int i = 0; i < 8; i++)
#pragma unroll
            for (int j = i; j < 8; j++) {
                const float mm = S[8 + t2++];
                quad += (i == j ? 1.f : 2.f) * w[i] * w[j] * mm;
            }
        const float cnt = (float)NP;
        const float bb = sc_b[c];
        const float sum = lin + cnt * bb;
        const float ss = quad + 2.f * bb * lin + cnt * bb * bb;
        const float m = sum / cnt, vv = ss / cnt - m * m;
        const float sc = sc_g[c] * rsqrtf(vv + BN_EPS);
        scsc[c] = sc; scsh[c] = sc_bt[c] - m * sc;
    }
    if (tid < 16) {
        const int c = tid;
        const float cP = 1.f / (float)NP;
        float m = ws[WS_S_Y4 + c] * cP, vv = ws[WS_SS_Y4 + c] * cP - m * m;
        float sc = p2_g[c] * rsqrtf(vv + BN_EPS);
        p2sc[c] = sc; p2sh[c] = p2_bt[c] - m * sc;
    }
    __syncthreads();

    const int p = blockIdx.x * 256 + tid;
    const int b = p >> 16;
    const int n = p & (NN - 1);
    const float4* __restrict__ y4 = (const float4*)(ws + WS_Y4);
    float x4[16];
#pragma unroll
    for (int cq = 0; cq < 4; cq++) {
        const float4 v = y4[cq * NP + p];
        const float yv[4] = {v.x, v.y, v.z, v.w};
#pragma unroll
        for (int j = 0; j < 4; j++) {
            const int c = cq * 4 + j;
            float y = yv[j] * p2sc[c] + p2sh[c];
            x4[c] = y > 0.f ? y : 0.f;
        }
    }
    float f[8];
#pragma unroll
    for (int i = 0; i < 8; i++) f[i] = feats[(b * 8 + i) * NN + n];
#pragma unroll
    for (int c = 0; c < 32; c++) {
        float s = scbs[c];
#pragma unroll
        for (int i = 0; i < 8; i++) s += f[i] * scws[c * 8 + i];
        s = s * scsc[c] + scsh[c];  // bn, no activation
        float m = b2s[c];
#pragma unroll
        for (int o = 0; o < 16; o++) m += x4[o] * w2s[c * 16 + o];
        float vv = m + s;
        out[(b * 32 + c) * NN + n] = vv > 0.f ? vv : 0.01f * vv;  // LeakyReLU(0.01)
    }
}

extern "C" void kernel_launch(void* const* d_in, const int* in_sizes, int n_in,
                              void* d_out, int out_size, void* d_ws, size_t ws_size,
                              hipStream_t stream) {
    (void)in_sizes; (void)n_in; (void)out_size; (void)ws_size;
    const float* coords = (const float*)d_in[0];
    const float* features = (const float*)d_in[1];
    const int* idx = (const int*)d_in[2];
    const float* w1 = (const float*)d_in[3];
    const float* b1 = (const float*)d_in[4];
    const float* lse1_w = (const float*)d_in[5];
    const float* lse1_b = (const float*)d_in[6];
    const float* lse1_g = (const float*)d_in[7];
    const float* lse1_bt = (const float*)d_in[8];
    const float* p1_sw = (const float*)d_in[9];
    const float* p1_w = (const float*)d_in[10];
    const float* p1_b = (const float*)d_in[11];
    const float* p1_g = (const float*)d_in[12];
    const float* p1_bt = (const float*)d_in[13];
    const float* lse2_w = (const float*)d_in[14];
    const float* lse2_b = (const float*)d_in[15];
    const float* lse2_g = (const float*)d_in[16];
    const float* lse2_bt = (const float*)d_in[17];
    const float* p2_sw = (const float*)d_in[18];
    const float* p2_w = (const float*)d_in[19];
    const float* p2_b = (const float*)d_in[20];
    const float* p2_g = (const float*)d_in[21];
    const float* p2_bt = (const float*)d_in[22];
    const float* w2 = (const float*)d_in[23];
    const float* b2 = (const float*)d_in[24];
    const float* sc_w = (const float*)d_in[25];
    const float* sc_b = (const float*)d_in[26];
    const float* sc_g = (const float*)d_in[27];
    const float* sc_bt = (const float*)d_in[28];
    float* ws = (float*)d_ws;
    float* out = (float*)d_out;
    float4* c4 = (float4*)(ws + WS_C4);

    (void)hipMemsetAsync(ws, 0, 144 * sizeof(float), stream);
    k_pack<<<NP / 256, 256, 0, stream>>>(coords, features, c4, ws);
    k_stats<<<NP / 256, 256, 0, stream>>>(c4, idx, ws);
    k_prep<<<1, 128, 0, stream>>>(lse1_w, lse1_b, lse1_g, lse1_bt,
                                  lse2_w, lse2_b, lse2_g, lse2_bt,
                                  p1_sw, p2_sw, ws);
    k_pools<<<2 * (NP / 256), 256, 0, stream>>>(c4, features, w1, b1,
                                                ws + WS_FW1, ws + WS_FW2,
                                                p1_w, p1_b, p2_w, p2_b, ws);
    k_pool2e<<<NP / 256, 256, 0, stream>>>(p1_g, p1_bt, p2_w, ws);
    k_final<<<NP / 256, 256, 0, stream>>>(features, w2, b2, sc_w, sc_b, p2_g, p2_bt,
                                          sc_g, sc_bt, ws, out);
}